// Round 7
// baseline (122.935 us; speedup 1.0000x reference)
//
#include <hip/hip_runtime.h>
#include <hip/hip_fp16.h>

static constexpr int N_ = 4;
static constexpr int C_ = 9;
static constexpr int D_ = 16;
static constexpr int HWp = 1024 * 1024;
static constexpr int CELLS = D_ * D_ * D_;   // 4096
static constexpr int NPAIR = 16 * 16 * 15;   // 3840 (r,g, b-pair) entries
static constexpr int PT = HWp / 4;           // 262144 float4 positions per image
static constexpr int TPB = 512;
static constexpr int BPI = 256;              // blocks per image; 1024 contiguous f4 each

__device__ __forceinline__ __half2 as_h2(unsigned u) {
    union { unsigned u; __half2 h; } v; v.u = u; return v.h;
}
__device__ __forceinline__ unsigned h2_as_u(__half2 h) {
    union { __half2 h; unsigned u; } v; v.h = h; return v.u;
}
__device__ __forceinline__ __half2 lerp2(__half2 a, __half2 b, __half2 t) {
    return __hfma2(__hsub2(b, a), t, a);
}
__device__ __forceinline__ float lerp1(float a, float b, float t) {
    return fmaf(b - a, t, a);
}

// Single kernel. Per-block: fold conv_w into a per-(r,g,b-pair) f16 LDS table
// (fold is exact algebra — slice+conv are both linear in grid; f16 quant err
// ~5e-4 << 3.2e-2 threshold), then trilinear-gather 4x ds_read_b128 per pixel
// while streaming guide->out in contiguous tiles (R5 structure, plain cached
// loads/stores — nt hints and the ws round-trip both regressed badly, R3/R4).
__global__ __launch_bounds__(TPB) void slice_kernel(
    const float* __restrict__ grid, const float* __restrict__ guide,
    const float* __restrict__ cw, const float* __restrict__ cbias,
    float* __restrict__ out)
{
    // entry e = (r*16+g)*15 + b : .x = half2(x_b, y_b), .y = half2(x_b1, y_b1),
    //                            .z = half2(z_b, z_b1), .w = pad
    __shared__ uint4 sPre[NPAIR];  // 60 KB

    const int n  = blockIdx.x >> 8;        // image
    const int bi = blockIdx.x & (BPI - 1); // tile within image

    // ---- In-block fold: grid (576 KB/image) is L2-resident; 27 FMA/cell ----
    {
        const float* g = grid + (size_t)n * C_ * CELLS;
        for (int e = threadIdx.x; e < NPAIR; e += TPB) {
            int rg = e / 15;
            int b  = e - rg * 15;
            int cell = rg * 16 + b;
            float a0 = 0.f, a1 = 0.f, a2 = 0.f;   // cell b
            float c0 = 0.f, c1 = 0.f, c2 = 0.f;   // cell b+1
#pragma unroll
            for (int c = 0; c < C_; ++c) {
                float v0 = g[(size_t)c * CELLS + cell];
                float v1 = g[(size_t)c * CELLS + cell + 1];
                a0 = fmaf(cw[c], v0, a0);
                a1 = fmaf(cw[12 + c], v0, a1);
                a2 = fmaf(cw[24 + c], v0, a2);
                c0 = fmaf(cw[c], v1, c0);
                c1 = fmaf(cw[12 + c], v1, c1);
                c2 = fmaf(cw[24 + c], v1, c2);
            }
            uint4 E;
            E.x = h2_as_u(__floats2half2_rn(a0, a1));
            E.y = h2_as_u(__floats2half2_rn(c0, c1));
            E.z = h2_as_u(__floats2half2_rn(a2, c2));
            E.w = 0;
            sPre[e] = E;
        }
    }
    __syncthreads();

    const float4* gR = (const float4*)(guide + (size_t)(n * 3 + 0) * HWp);
    const float4* gG = (const float4*)(guide + (size_t)(n * 3 + 1) * HWp);
    const float4* gB = (const float4*)(guide + (size_t)(n * 3 + 2) * HWp);
    float4* oR = (float4*)(out + (size_t)(n * 3 + 0) * HWp);
    float4* oG = (float4*)(out + (size_t)(n * 3 + 1) * HWp);
    float4* oB = (float4*)(out + (size_t)(n * 3 + 2) * HWp);

    const float w0r = cw[9],  w0g = cw[10], w0b = cw[11];
    const float w1r = cw[21], w1g = cw[22], w1b = cw[23];
    const float w2r = cw[33], w2g = cw[34], w2b = cw[35];
    const float bi0 = cbias[0], bi1 = cbias[1], bi2 = cbias[2];

    const int base0 = bi * (PT / BPI);  // 1024 contiguous f4 per block

#pragma unroll
    for (int it = 0; it < (PT / BPI) / TPB; ++it) {
        const int p4 = base0 + it * TPB + threadIdx.x;
        float4 r4 = gR[p4];
        float4 g4 = gG[p4];
        float4 b4 = gB[p4];

        float rr[4] = {r4.x, r4.y, r4.z, r4.w};
        float gg[4] = {g4.x, g4.y, g4.z, g4.w};
        float bb[4] = {b4.x, b4.y, b4.z, b4.w};
        float o0[4], o1[4], o2[4];

#pragma unroll
        for (int j = 0; j < 4; ++j) {
            float cr = fminf(fmaxf(rr[j], 0.f), 1.f) * 15.f;
            float cg = fminf(fmaxf(gg[j], 0.f), 1.f) * 15.f;
            float cb = fminf(fmaxf(bb[j], 0.f), 1.f) * 15.f;
            int ir = min((int)cr, 14);   // >=0, trunc == floor
            int ig = min((int)cg, 14);
            int ib = min((int)cb, 14);
            float fr = cr - (float)ir;
            float fg = cg - (float)ig;
            float fb = cb - (float)ib;

            int e = (ir * 16 + ig) * 15 + ib;
            uint4 E00 = sPre[e];
            uint4 E01 = sPre[e + 15];
            uint4 E10 = sPre[e + 240];
            uint4 E11 = sPre[e + 255];

            __half  fbh = __float2half_rn(fb);
            __half2 fb2 = __half2half2(fbh);
            __half2 fg2 = __half2half2(__float2half_rn(fg));
            __half2 fr2 = __half2half2(__float2half_rn(fr));

            // b-lerp: xy packed, z across the (z_b, z_b1) halves
            __half2 xy00 = lerp2(as_h2(E00.x), as_h2(E00.y), fb2);
            __half2 xy01 = lerp2(as_h2(E01.x), as_h2(E01.y), fb2);
            __half2 xy10 = lerp2(as_h2(E10.x), as_h2(E10.y), fb2);
            __half2 xy11 = lerp2(as_h2(E11.x), as_h2(E11.y), fb2);
            __half2 z00p = as_h2(E00.z), z01p = as_h2(E01.z);
            __half2 z10p = as_h2(E10.z), z11p = as_h2(E11.z);
            __half z00 = __hfma(__hsub(__high2half(z00p), __low2half(z00p)), fbh, __low2half(z00p));
            __half z01 = __hfma(__hsub(__high2half(z01p), __low2half(z01p)), fbh, __low2half(z01p));
            __half z10 = __hfma(__hsub(__high2half(z10p), __low2half(z10p)), fbh, __low2half(z10p));
            __half z11 = __hfma(__hsub(__high2half(z11p), __low2half(z11p)), fbh, __low2half(z11p));

            // g-lerp
            __half2 xy0 = lerp2(xy00, xy01, fg2);
            __half2 xy1 = lerp2(xy10, xy11, fg2);
            __half2 zA  = __halves2half2(z00, z10);
            __half2 zB  = __halves2half2(z01, z11);
            __half2 zG  = lerp2(zA, zB, fg2);   // (z0, z1)

            // r-lerp
            __half2 xyF = lerp2(xy0, xy1, fr2);
            __half  zF  = __hfma(__hsub(__high2half(zG), __low2half(zG)),
                                 __float2half_rn(fr), __low2half(zG));

            float vx = __half2float(__low2half(xyF));
            float vy = __half2float(__high2half(xyF));
            float vz = __half2float(zF);

            o0[j] = vx + fmaf(w0r, rr[j], fmaf(w0g, gg[j], fmaf(w0b, bb[j], bi0)));
            o1[j] = vy + fmaf(w1r, rr[j], fmaf(w1g, gg[j], fmaf(w1b, bb[j], bi1)));
            o2[j] = vz + fmaf(w2r, rr[j], fmaf(w2g, gg[j], fmaf(w2b, bb[j], bi2)));
        }

        oR[p4] = make_float4(o0[0], o0[1], o0[2], o0[3]);
        oG[p4] = make_float4(o1[0], o1[1], o1[2], o1[3]);
        oB[p4] = make_float4(o2[0], o2[1], o2[2], o2[3]);
    }
}

extern "C" void kernel_launch(void* const* d_in, const int* in_sizes, int n_in,
                              void* d_out, int out_size, void* d_ws, size_t ws_size,
                              hipStream_t stream) {
    const float* grid  = (const float*)d_in[0];
    const float* guide = (const float*)d_in[1];
    const float* cw    = (const float*)d_in[2];
    const float* cb    = (const float*)d_in[3];
    float* out = (float*)d_out;

    slice_kernel<<<N_ * BPI, TPB, 0, stream>>>(grid, guide, cw, cb, out);
}

// Round 8
// 120.004 us; speedup vs baseline: 1.0244x; 1.0244x over previous
//
#include <hip/hip_runtime.h>
#include <hip/hip_bf16.h>

static constexpr int N_ = 4;
static constexpr int C_ = 9;
static constexpr int D_ = 16;
static constexpr int HWp = 1024 * 1024;
static constexpr int CELLS = D_ * D_ * D_;  // 4096
static constexpr int PT = HWp / 4;          // 262144 float4 positions per image
static constexpr int TPB = 256;             // 4 waves/block -> 5 blocks resident (32KB LDS)
static constexpr int BPI = 512;             // blocks per image; 512 contiguous f4 each

__device__ __forceinline__ void unpack3(uint2 w, float& x, float& y, float& z) {
    x = __uint_as_float(w.x << 16);
    y = __uint_as_float(w.x & 0xFFFF0000u);
    z = __uint_as_float(w.y << 16);
}

__device__ __forceinline__ float lerp1(float a, float b, float t) {
    return fmaf(b - a, t, a);
}

// Single self-contained kernel (R5 structure — the known-good one):
// per-block fold of conv_w into a bf16 LDS table (fold is exact algebra,
// bf16 quant err ~5e-3 << 3.2e-2), then 8x ds_read_b64 trilinear gather
// while streaming guide->out in contiguous tiles. Plain cached loads/stores
// (nt hints regressed 3x traffic in R3; ws round-trip regressed in R4;
// 60KB f16-pair table regressed occupancy+VALU in R6).
// This round's single change: TPB 512->256, BPI 256->512 for higher
// residency (LDS caps 5 blocks/CU) and finer tail balance.
__global__ __launch_bounds__(TPB) void slice_kernel(
    const float* __restrict__ grid, const float* __restrict__ guide,
    const float* __restrict__ cw, const float* __restrict__ cbias,
    float* __restrict__ out)
{
    __shared__ uint2 sPre[CELLS];  // 32 KB: bf16 x,y,z per cell

    const int n  = blockIdx.x >> 9;        // image (BPI = 512)
    const int bi = blockIdx.x & (BPI - 1); // tile within image

    // ---- In-block fold: 16 cells per thread, coalesced dword reads of grid ----
    {
        const float* g = grid + (size_t)n * C_ * CELLS;
#pragma unroll
        for (int k = 0; k < CELLS / TPB; ++k) {
            int cell = k * TPB + threadIdx.x;
            float a0 = 0.f, a1 = 0.f, a2 = 0.f;
#pragma unroll
            for (int c = 0; c < C_; ++c) {
                float v = g[(size_t)c * CELLS + cell];
                a0 = fmaf(cw[c], v, a0);
                a1 = fmaf(cw[12 + c], v, a1);
                a2 = fmaf(cw[24 + c], v, a2);
            }
            unsigned short b0 = __bfloat16_as_ushort(__float2bfloat16(a0));
            unsigned short b1 = __bfloat16_as_ushort(__float2bfloat16(a1));
            unsigned short b2 = __bfloat16_as_ushort(__float2bfloat16(a2));
            uint2 v;
            v.x = (unsigned)b0 | ((unsigned)b1 << 16);
            v.y = (unsigned)b2;
            sPre[cell] = v;
        }
    }
    __syncthreads();

    const float4* gR = (const float4*)(guide + (size_t)(n * 3 + 0) * HWp);
    const float4* gG = (const float4*)(guide + (size_t)(n * 3 + 1) * HWp);
    const float4* gB = (const float4*)(guide + (size_t)(n * 3 + 2) * HWp);
    float4* oR = (float4*)(out + (size_t)(n * 3 + 0) * HWp);
    float4* oG = (float4*)(out + (size_t)(n * 3 + 1) * HWp);
    float4* oB = (float4*)(out + (size_t)(n * 3 + 2) * HWp);

    const float w0r = cw[9],  w0g = cw[10], w0b = cw[11];
    const float w1r = cw[21], w1g = cw[22], w1b = cw[23];
    const float w2r = cw[33], w2g = cw[34], w2b = cw[35];
    const float bi0 = cbias[0], bi1 = cbias[1], bi2 = cbias[2];

    const int base0 = bi * (PT / BPI);  // 512 contiguous f4 per block

#pragma unroll
    for (int it = 0; it < (PT / BPI) / TPB; ++it) {
        const int p4 = base0 + it * TPB + threadIdx.x;
        float4 r4 = gR[p4];
        float4 g4 = gG[p4];
        float4 b4 = gB[p4];

        float rr[4] = {r4.x, r4.y, r4.z, r4.w};
        float gg[4] = {g4.x, g4.y, g4.z, g4.w};
        float bb[4] = {b4.x, b4.y, b4.z, b4.w};
        float o0[4], o1[4], o2[4];

#pragma unroll
        for (int j = 0; j < 4; ++j) {
            float cr = fminf(fmaxf(rr[j], 0.f), 1.f) * 15.f;
            float cg = fminf(fmaxf(gg[j], 0.f), 1.f) * 15.f;
            float cb = fminf(fmaxf(bb[j], 0.f), 1.f) * 15.f;
            int ir = min((int)cr, 14);   // >=0, trunc == floor
            int ig = min((int)cg, 14);
            int ib = min((int)cb, 14);
            float fr = cr - (float)ir;
            float fg = cg - (float)ig;
            float fb = cb - (float)ib;
            int base = (ir * 16 + ig) * 16 + ib;

            uint2 q000 = sPre[base];
            uint2 q001 = sPre[base + 1];
            uint2 q010 = sPre[base + 16];
            uint2 q011 = sPre[base + 17];
            uint2 q100 = sPre[base + 256];
            uint2 q101 = sPre[base + 257];
            uint2 q110 = sPre[base + 272];
            uint2 q111 = sPre[base + 273];

            float ax, ay, az, bx, by, bz;
            float v00x, v00y, v00z, v01x, v01y, v01z;
            float v10x, v10y, v10z, v11x, v11y, v11z;

            unpack3(q000, ax, ay, az); unpack3(q001, bx, by, bz);
            v00x = lerp1(ax, bx, fb); v00y = lerp1(ay, by, fb); v00z = lerp1(az, bz, fb);
            unpack3(q010, ax, ay, az); unpack3(q011, bx, by, bz);
            v01x = lerp1(ax, bx, fb); v01y = lerp1(ay, by, fb); v01z = lerp1(az, bz, fb);
            unpack3(q100, ax, ay, az); unpack3(q101, bx, by, bz);
            v10x = lerp1(ax, bx, fb); v10y = lerp1(ay, by, fb); v10z = lerp1(az, bz, fb);
            unpack3(q110, ax, ay, az); unpack3(q111, bx, by, bz);
            v11x = lerp1(ax, bx, fb); v11y = lerp1(ay, by, fb); v11z = lerp1(az, bz, fb);

            float v0x = lerp1(v00x, v01x, fg);
            float v0y = lerp1(v00y, v01y, fg);
            float v0z = lerp1(v00z, v01z, fg);
            float v1x = lerp1(v10x, v11x, fg);
            float v1y = lerp1(v10y, v11y, fg);
            float v1z = lerp1(v10z, v11z, fg);

            float vx = lerp1(v0x, v1x, fr);
            float vy = lerp1(v0y, v1y, fr);
            float vz = lerp1(v0z, v1z, fr);

            o0[j] = vx + fmaf(w0r, rr[j], fmaf(w0g, gg[j], fmaf(w0b, bb[j], bi0)));
            o1[j] = vy + fmaf(w1r, rr[j], fmaf(w1g, gg[j], fmaf(w1b, bb[j], bi1)));
            o2[j] = vz + fmaf(w2r, rr[j], fmaf(w2g, gg[j], fmaf(w2b, bb[j], bi2)));
        }

        oR[p4] = make_float4(o0[0], o0[1], o0[2], o0[3]);
        oG[p4] = make_float4(o1[0], o1[1], o1[2], o1[3]);
        oB[p4] = make_float4(o2[0], o2[1], o2[2], o2[3]);
    }
}

extern "C" void kernel_launch(void* const* d_in, const int* in_sizes, int n_in,
                              void* d_out, int out_size, void* d_ws, size_t ws_size,
                              hipStream_t stream) {
    const float* grid  = (const float*)d_in[0];
    const float* guide = (const float*)d_in[1];
    const float* cw    = (const float*)d_in[2];
    const float* cb    = (const float*)d_in[3];
    float* out = (float*)d_out;

    slice_kernel<<<N_ * BPI, TPB, 0, stream>>>(grid, guide, cw, cb, out);
}

// Round 9
// 115.010 us; speedup vs baseline: 1.0689x; 1.0434x over previous
//
#include <hip/hip_runtime.h>
#include <hip/hip_bf16.h>

static constexpr int N_ = 4;
static constexpr int C_ = 9;
static constexpr int D_ = 16;
static constexpr int HWp = 1024 * 1024;
static constexpr int CELLS = D_ * D_ * D_;  // 4096
static constexpr int PT = HWp / 4;          // 262144 float4 positions per image
static constexpr int TPB = 512;
static constexpr int BPI = 256;             // blocks per image; 1024 contiguous f4 each

__device__ __forceinline__ void unpack3(uint2 w, float& x, float& y, float& z) {
    x = __uint_as_float(w.x << 16);
    y = __uint_as_float(w.x & 0xFFFF0000u);
    z = __uint_as_float(w.y << 16);
}

__device__ __forceinline__ float lerp1(float a, float b, float t) {
    return fmaf(b - a, t, a);
}

// Final configuration — measured best (R5: bench 114.5 us).
// Single self-contained kernel: per-block fold of conv_w into a bf16 LDS
// table (slice+conv are both linear in grid => fold is exact algebra; bf16
// quant err ~5e-3 << 3.2e-2 threshold), then 8x ds_read_b64 trilinear
// gather per pixel while streaming guide->out in contiguous tiles.
// Measured dead-ends, do not revisit:
//  - nontemporal hints: 3x HBM traffic blowup (R3)
//  - fold->workspace round-trip + 2 dispatches: traffic blowup (R4)
//  - 60 KB f16 pair-table (4x b128 gathers): occupancy+VALU+conflicts all
//    regressed (R6)
//  - TPB=256/BPI=512: wave cap already binding, fold cost doubles (R7)
__global__ __launch_bounds__(TPB) void slice_kernel(
    const float* __restrict__ grid, const float* __restrict__ guide,
    const float* __restrict__ cw, const float* __restrict__ cbias,
    float* __restrict__ out)
{
    __shared__ uint2 sPre[CELLS];  // 32 KB: bf16 x,y,z per cell

    const int n  = blockIdx.x >> 8;        // image (BPI = 256)
    const int bi = blockIdx.x & (BPI - 1); // tile within image

    // ---- In-block fold: 8 cells per thread, coalesced dword reads of grid ----
    {
        const float* g = grid + (size_t)n * C_ * CELLS;
#pragma unroll
        for (int k = 0; k < CELLS / TPB; ++k) {
            int cell = k * TPB + threadIdx.x;
            float a0 = 0.f, a1 = 0.f, a2 = 0.f;
#pragma unroll
            for (int c = 0; c < C_; ++c) {
                float v = g[(size_t)c * CELLS + cell];
                a0 = fmaf(cw[c], v, a0);
                a1 = fmaf(cw[12 + c], v, a1);
                a2 = fmaf(cw[24 + c], v, a2);
            }
            unsigned short b0 = __bfloat16_as_ushort(__float2bfloat16(a0));
            unsigned short b1 = __bfloat16_as_ushort(__float2bfloat16(a1));
            unsigned short b2 = __bfloat16_as_ushort(__float2bfloat16(a2));
            uint2 v;
            v.x = (unsigned)b0 | ((unsigned)b1 << 16);
            v.y = (unsigned)b2;
            sPre[cell] = v;
        }
    }
    __syncthreads();

    const float4* gR = (const float4*)(guide + (size_t)(n * 3 + 0) * HWp);
    const float4* gG = (const float4*)(guide + (size_t)(n * 3 + 1) * HWp);
    const float4* gB = (const float4*)(guide + (size_t)(n * 3 + 2) * HWp);
    float4* oR = (float4*)(out + (size_t)(n * 3 + 0) * HWp);
    float4* oG = (float4*)(out + (size_t)(n * 3 + 1) * HWp);
    float4* oB = (float4*)(out + (size_t)(n * 3 + 2) * HWp);

    const float w0r = cw[9],  w0g = cw[10], w0b = cw[11];
    const float w1r = cw[21], w1g = cw[22], w1b = cw[23];
    const float w2r = cw[33], w2g = cw[34], w2b = cw[35];
    const float bi0 = cbias[0], bi1 = cbias[1], bi2 = cbias[2];

    const int base0 = bi * (PT / BPI);  // 1024 contiguous f4 per block

#pragma unroll
    for (int it = 0; it < (PT / BPI) / TPB; ++it) {
        const int p4 = base0 + it * TPB + threadIdx.x;
        float4 r4 = gR[p4];
        float4 g4 = gG[p4];
        float4 b4 = gB[p4];

        float rr[4] = {r4.x, r4.y, r4.z, r4.w};
        float gg[4] = {g4.x, g4.y, g4.z, g4.w};
        float bb[4] = {b4.x, b4.y, b4.z, b4.w};
        float o0[4], o1[4], o2[4];

#pragma unroll
        for (int j = 0; j < 4; ++j) {
            float cr = fminf(fmaxf(rr[j], 0.f), 1.f) * 15.f;
            float cg = fminf(fmaxf(gg[j], 0.f), 1.f) * 15.f;
            float cb = fminf(fmaxf(bb[j], 0.f), 1.f) * 15.f;
            int ir = min((int)cr, 14);   // >=0, trunc == floor
            int ig = min((int)cg, 14);
            int ib = min((int)cb, 14);
            float fr = cr - (float)ir;
            float fg = cg - (float)ig;
            float fb = cb - (float)ib;
            int base = (ir * 16 + ig) * 16 + ib;

            uint2 q000 = sPre[base];
            uint2 q001 = sPre[base + 1];
            uint2 q010 = sPre[base + 16];
            uint2 q011 = sPre[base + 17];
            uint2 q100 = sPre[base + 256];
            uint2 q101 = sPre[base + 257];
            uint2 q110 = sPre[base + 272];
            uint2 q111 = sPre[base + 273];

            float ax, ay, az, bx, by, bz;
            float v00x, v00y, v00z, v01x, v01y, v01z;
            float v10x, v10y, v10z, v11x, v11y, v11z;

            unpack3(q000, ax, ay, az); unpack3(q001, bx, by, bz);
            v00x = lerp1(ax, bx, fb); v00y = lerp1(ay, by, fb); v00z = lerp1(az, bz, fb);
            unpack3(q010, ax, ay, az); unpack3(q011, bx, by, bz);
            v01x = lerp1(ax, bx, fb); v01y = lerp1(ay, by, fb); v01z = lerp1(az, bz, fb);
            unpack3(q100, ax, ay, az); unpack3(q101, bx, by, bz);
            v10x = lerp1(ax, bx, fb); v10y = lerp1(ay, by, fb); v10z = lerp1(az, bz, fb);
            unpack3(q110, ax, ay, az); unpack3(q111, bx, by, bz);
            v11x = lerp1(ax, bx, fb); v11y = lerp1(ay, by, fb); v11z = lerp1(az, bz, fb);

            float v0x = lerp1(v00x, v01x, fg);
            float v0y = lerp1(v00y, v01y, fg);
            float v0z = lerp1(v00z, v01z, fg);
            float v1x = lerp1(v10x, v11x, fg);
            float v1y = lerp1(v10y, v11y, fg);
            float v1z = lerp1(v10z, v11z, fg);

            float vx = lerp1(v0x, v1x, fr);
            float vy = lerp1(v0y, v1y, fr);
            float vz = lerp1(v0z, v1z, fr);

            o0[j] = vx + fmaf(w0r, rr[j], fmaf(w0g, gg[j], fmaf(w0b, bb[j], bi0)));
            o1[j] = vy + fmaf(w1r, rr[j], fmaf(w1g, gg[j], fmaf(w1b, bb[j], bi1)));
            o2[j] = vz + fmaf(w2r, rr[j], fmaf(w2g, gg[j], fmaf(w2b, bb[j], bi2)));
        }

        oR[p4] = make_float4(o0[0], o0[1], o0[2], o0[3]);
        oG[p4] = make_float4(o1[0], o1[1], o1[2], o1[3]);
        oB[p4] = make_float4(o2[0], o2[1], o2[2], o2[3]);
    }
}

extern "C" void kernel_launch(void* const* d_in, const int* in_sizes, int n_in,
                              void* d_out, int out_size, void* d_ws, size_t ws_size,
                              hipStream_t stream) {
    const float* grid  = (const float*)d_in[0];
    const float* guide = (const float*)d_in[1];
    const float* cw    = (const float*)d_in[2];
    const float* cb    = (const float*)d_in[3];
    float* out = (float*)d_out;

    slice_kernel<<<N_ * BPI, TPB, 0, stream>>>(grid, guide, cw, cb, out);
}